// Round 5
// baseline (548.419 us; speedup 1.0000x reference)
//
#include <hip/hip_runtime.h>
#include <math.h>

// KGATConv: N=50000, E=800000, D=64, R=16, fp32.
// R11: proj table ELIMINATED. Edges counting-sorted by etype (LDS per-block
// histogram -> 16-column wave scan -> fill); fused k_attE processes 64
// same-type edges per block: gather src/dst nfeat rows (12.8MB table,
// L2/L3-resident vs the old 102MB proj table), W_r in LDS, two MFMA GEMMs,
// tanh-dot in-register, scatter att to dst-CSR slot. Removes the 102MB
// proj HBM write + its gather re-read entirely. k_agg/k_bi/dst-CSR unchanged.

#define DIM 64
#define PA 72

typedef _Float16 half8 __attribute__((ext_vector_type(8)));
typedef float f32x4 __attribute__((ext_vector_type(4)));

__device__ __forceinline__ float4 f4zero() { return make_float4(0.f, 0.f, 0.f, 0.f); }

__device__ __forceinline__ float fast_tanh(float x) {
    float ex = __expf(2.0f * x);
    return 1.0f - 2.0f / (ex + 1.0f);
}

// ---------------------------------------------------------------------------
// dst-CSR build: k_hist's atomic return value is the within-segment rank.
// ---------------------------------------------------------------------------
__global__ __launch_bounds__(256) void k_hist(const int* __restrict__ dst,
                                              int* __restrict__ deg,
                                              int* __restrict__ rank, int E) {
    int e = blockIdx.x * 256 + threadIdx.x;
    if (e < E) rank[e] = atomicAdd(&deg[dst[e]], 1);
}

__global__ __launch_bounds__(256) void k_scan1(const int* __restrict__ deg,
                                               int* __restrict__ epart,
                                               int* __restrict__ bsum, int N) {
    __shared__ int sh[256];
    int i = blockIdx.x * 256 + threadIdx.x;
    int t = threadIdx.x;
    int v = (i < N) ? deg[i] : 0;
    sh[t] = v;
    __syncthreads();
#pragma unroll
    for (int d = 1; d < 256; d <<= 1) {
        int o = (t >= d) ? sh[t - d] : 0;
        __syncthreads();
        sh[t] += o;
        __syncthreads();
    }
    if (i < N) epart[i] = sh[t] - v;
    if (t == 255) bsum[blockIdx.x] = sh[255];
}

__global__ __launch_bounds__(1024) void k_scan2(const int* __restrict__ epart,
                                                const int* __restrict__ bsum,
                                                int nb,
                                                int* __restrict__ off,
                                                int N, int E) {
    __shared__ int bx[256];
    int t = threadIdx.x;
    int v = 0;
    if (t < 256) {
        v = (t < nb) ? bsum[t] : 0;
        bx[t] = v;
    }
    __syncthreads();
#pragma unroll
    for (int d = 1; d < 256; d <<= 1) {
        int o = 0;
        if (t < 256 && t >= d) o = bx[t - d];
        __syncthreads();
        if (t < 256) bx[t] += o;
        __syncthreads();
    }
    if (t < 256) bx[t] -= v;   // exclusive block prefix
    __syncthreads();
    for (int i = t; i < N; i += 1024)
        off[i] = epart[i] + bx[i >> 8];
    if (t == 0) off[N] = E;
}

// ---------------------------------------------------------------------------
// etype counting sort (3 kernels). bh is [16][nbe] column-major per type.
// ---------------------------------------------------------------------------
__global__ __launch_bounds__(256) void k_thist(const int* __restrict__ etype,
                                               int* __restrict__ bh,
                                               int nbe, int E) {
    __shared__ int h[16];
    const int tx = threadIdx.x, b = blockIdx.x;
    if (tx < 16) h[tx] = 0;
    __syncthreads();
    int e = b * 256 + tx;
    if (e < E) atomicAdd(&h[etype[e]], 1);
    __syncthreads();
    if (tx < 16) bh[(size_t)tx * nbe + b] = h[tx];
}

// 1 block, 1024 threads = 16 waves; wave w scans type w's block counts.
// hdr[0..16] = tstart (exclusive prefix of type counts, +end)
// hdr[17..33] = tilePre (exclusive prefix of per-type 64-edge tile counts, +end)
__global__ __launch_bounds__(1024) void k_tscan(int* __restrict__ bh, int nbe,
                                                int* __restrict__ hdr) {
    __shared__ int cntS[16];
    __shared__ int tstartS[16];
    const int tx = threadIdx.x;
    const int w = tx >> 6;
    const int lane = tx & 63;
    int* row = bh + (size_t)w * nbe;

    int run = 0;
    for (int i0 = 0; i0 < nbe; i0 += 64) {
        int idx = i0 + lane;
        int v = (idx < nbe) ? row[idx] : 0;
        int incl = v;
#pragma unroll
        for (int d = 1; d < 64; d <<= 1) {
            int o = __shfl_up(incl, d);
            if (lane >= d) incl += o;
        }
        if (idx < nbe) row[idx] = run + (incl - v);   // excl prefix within type
        run += __shfl(incl, 63);
    }
    if (lane == 0) cntS[w] = run;
    __syncthreads();
    if (tx == 0) {
        int ts = 0, tp = 0;
        for (int r = 0; r < 16; ++r) {
            tstartS[r] = ts;
            hdr[r] = ts;
            hdr[17 + r] = tp;
            ts += cntS[r];
            tp += (cntS[r] + 63) >> 6;
        }
        hdr[16] = ts;
        hdr[33] = tp;
    }
    __syncthreads();
    const int t0 = tstartS[w];
    for (int i0 = 0; i0 < nbe; i0 += 64) {
        int idx = i0 + lane;
        if (idx < nbe) row[idx] += t0;   // absolute slot base per (type, block)
    }
}

__global__ __launch_bounds__(256) void k_tfill(const int* __restrict__ src,
                                               const int* __restrict__ dst,
                                               const int* __restrict__ etype,
                                               const int* __restrict__ rank,
                                               const int* __restrict__ off,
                                               const int* __restrict__ bh, int nbe,
                                               int* __restrict__ sS,
                                               int* __restrict__ dS,
                                               int* __restrict__ pS,
                                               int* __restrict__ eS, int E) {
    __shared__ int h[16];
    const int tx = threadIdx.x, b = blockIdx.x;
    if (tx < 16) h[tx] = 0;
    __syncthreads();
    int e = b * 256 + tx;
    if (e < E) {
        int r = etype[e];
        int mr = atomicAdd(&h[r], 1);   // any bijective within-(block,type) rank
        int slot = bh[(size_t)r * nbe + b] + mr;
        int d = dst[e];
        sS[slot] = src[e];
        dS[slot] = d;
        pS[slot] = off[d] + rank[e];
        eS[slot] = e;
    }
}

// ---------------------------------------------------------------------------
// Fused attention: 64 same-type edges per block.
// T = nfeat[src]@W_r, H = nfeat[dst]@W_r (MFMA, f16 in / f32 acc),
// att = rowdot(T, tanh(H + efeat)), scattered to dst-CSR slot.
// ---------------------------------------------------------------------------
__global__ __launch_bounds__(256) void k_attE(const float* __restrict__ nfeat,
                                              const float* __restrict__ efeat,
                                              const float* __restrict__ relW,
                                              const int* __restrict__ hdr,
                                              const int* __restrict__ sS,
                                              const int* __restrict__ dS,
                                              const int* __restrict__ pS,
                                              const int* __restrict__ eS,
                                              float* __restrict__ att_s,
                                              int* __restrict__ src_s) {
    __shared__ _Float16 shS[64 * PA];
    __shared__ _Float16 shD[64 * PA];
    __shared__ _Float16 shB[64 * PA];

    const int bid = blockIdx.x;
    if (bid >= hdr[33]) return;
    int r = 0;
    while (r < 15 && bid >= hdr[17 + r + 1]) ++r;
    const int e0 = hdr[r] + ((bid - hdr[17 + r]) << 6);
    const int cnt = min(64, hdr[r + 1] - e0);

    const int tx = threadIdx.x;

    // W_r -> shB in B-fragment layout (shB[col*PA + k] = W[k][col])
    const float4* Wr4 = (const float4*)(relW + (size_t)r * DIM * DIM);
#pragma unroll
    for (int i = 0; i < 4; ++i) {
        int idx = tx + 256 * i;
        int d = idx >> 4, c = (idx & 15) * 4;
        float4 v = Wr4[idx];
        shB[(c + 0) * PA + d] = (_Float16)v.x;
        shB[(c + 1) * PA + d] = (_Float16)v.y;
        shB[(c + 2) * PA + d] = (_Float16)v.z;
        shB[(c + 3) * PA + d] = (_Float16)v.w;
    }
    // gather src/dst nfeat rows (16 threads x float4 per row)
#pragma unroll
    for (int i = 0; i < 4; ++i) {
        int idx = tx + 256 * i;
        int row = idx >> 4, c = idx & 15;
        bool ok = (row < cnt);
        int sn = ok ? sS[e0 + row] : 0;
        int dn = ok ? dS[e0 + row] : 0;
        float4 a = ok ? *(const float4*)&nfeat[(size_t)sn * DIM + c * 4] : f4zero();
        float4 b = ok ? *(const float4*)&nfeat[(size_t)dn * DIM + c * 4] : f4zero();
        _Float16* p1 = &shS[row * PA + c * 4];
        _Float16* p2 = &shD[row * PA + c * 4];
        p1[0] = (_Float16)a.x; p1[1] = (_Float16)a.y;
        p1[2] = (_Float16)a.z; p1[3] = (_Float16)a.w;
        p2[0] = (_Float16)b.x; p2[1] = (_Float16)b.y;
        p2[2] = (_Float16)b.z; p2[3] = (_Float16)b.w;
    }
    __syncthreads();

    const int w = tx >> 6;
    const int lane = tx & 63;
    const int lm = lane & 15;
    const int lq = lane >> 4;
    const int m0 = w * 16;

    half8 as0 = *(const half8*)&shS[(m0 + lm) * PA + 0 * 32 + lq * 8];
    half8 as1 = *(const half8*)&shS[(m0 + lm) * PA + 1 * 32 + lq * 8];
    half8 ad0 = *(const half8*)&shD[(m0 + lm) * PA + 0 * 32 + lq * 8];
    half8 ad1 = *(const half8*)&shD[(m0 + lm) * PA + 1 * 32 + lq * 8];

    f32x4 T[4], H[4];
#pragma unroll
    for (int ct = 0; ct < 4; ++ct) {
        half8 b0 = *(const half8*)&shB[(ct * 16 + lm) * PA + 0 * 32 + lq * 8];
        half8 b1 = *(const half8*)&shB[(ct * 16 + lm) * PA + 1 * 32 + lq * 8];
        f32x4 c1 = {0.f, 0.f, 0.f, 0.f};
        f32x4 c2 = {0.f, 0.f, 0.f, 0.f};
        c1 = __builtin_amdgcn_mfma_f32_16x16x32_f16(as0, b0, c1, 0, 0, 0);
        c1 = __builtin_amdgcn_mfma_f32_16x16x32_f16(as1, b1, c1, 0, 0, 0);
        c2 = __builtin_amdgcn_mfma_f32_16x16x32_f16(ad0, b0, c2, 0, 0, 0);
        c2 = __builtin_amdgcn_mfma_f32_16x16x32_f16(ad1, b1, c2, 0, 0, 0);
        T[ct] = c1;
        H[ct] = c2;
    }

    // per-edge indices for efeat (row = m0 + lq*4 + i)
    int ei[4];
#pragma unroll
    for (int i = 0; i < 4; ++i) {
        int row = m0 + lq * 4 + i;
        ei[i] = (row < cnt) ? eS[e0 + row] : -1;
    }

    float part[4] = {0.f, 0.f, 0.f, 0.f};
#pragma unroll
    for (int ct = 0; ct < 4; ++ct) {
        int col = ct * 16 + lm;
#pragma unroll
        for (int i = 0; i < 4; ++i) {
            float ef = (ei[i] >= 0)
                ? __builtin_nontemporal_load(&efeat[(size_t)ei[i] * DIM + col])
                : 0.f;
            part[i] = fmaf(T[ct][i], fast_tanh(H[ct][i] + ef), part[i]);
        }
    }
    // reduce across the 16-lane (lm) group; lanes of a group are contiguous
#pragma unroll
    for (int i = 0; i < 4; ++i) {
        part[i] += __shfl_xor(part[i], 1);
        part[i] += __shfl_xor(part[i], 2);
        part[i] += __shfl_xor(part[i], 4);
        part[i] += __shfl_xor(part[i], 8);
    }
    if (lm == 0) {
#pragma unroll
        for (int i = 0; i < 4; ++i) {
            int row = m0 + lq * 4 + i;
            if (row < cnt) {
                int p = pS[e0 + row];
                att_s[p] = part[i];
                src_s[p] = sS[e0 + row];
            }
        }
    }
}

// ---------------------------------------------------------------------------
// Pure softmax + aggregation. Wave per node, NO LDS.
// Quarter-wave float4 gathers: one VMEM instr covers 4 nfeat rows.
// ---------------------------------------------------------------------------
__global__ __launch_bounds__(256) void k_agg(const float* __restrict__ att_s,
                                             const int* __restrict__ src_s,
                                             const float* __restrict__ nfeat,
                                             const int* __restrict__ off,
                                             float* __restrict__ hn, int N) {
    const int node = blockIdx.x * 4 + (threadIdx.x >> 6);
    if (node >= N) return;
    const int lane = threadIdx.x & 63;
    const int qw = lane >> 4;   // quarter-wave index (row slot)
    const int ql = lane & 15;   // lane within quarter (4-dim slice)

    const int jb = off[node];
    const int je = off[node + 1];

    float m = -INFINITY;
    for (int j0 = jb; j0 < je; j0 += 64) {
        int j = j0 + lane;
        float a = (j < je) ? att_s[j] : -INFINITY;
        m = fmaxf(m, a);
    }
#pragma unroll
    for (int ms = 32; ms; ms >>= 1) m = fmaxf(m, __shfl_xor(m, ms));

    float pl = 0.f;
    f32x4 acc = {0.f, 0.f, 0.f, 0.f};
    for (int j0 = jb; j0 < je; j0 += 64) {
        int j = j0 + lane;
        int cnt = min(64, je - j0);
        float a = (j < je) ? att_s[j] : -INFINITY;
        float p = __expf(a - m);
        int s = (j < je) ? src_s[j] : 0;
        pl += p;

        int jj = 0;
        for (; jj + 15 < cnt; jj += 16) {
            float pj[4]; int sj[4]; f32x4 x[4];
#pragma unroll
            for (int u = 0; u < 4; ++u) {
                int eidx = jj + u * 4 + qw;
                pj[u] = __shfl(p, eidx);
                sj[u] = __shfl(s, eidx);
            }
#pragma unroll
            for (int u = 0; u < 4; ++u)
                x[u] = *(const f32x4*)&nfeat[(size_t)sj[u] * DIM + ql * 4];
#pragma unroll
            for (int u = 0; u < 4; ++u) {
                acc[0] = fmaf(pj[u], x[u][0], acc[0]);
                acc[1] = fmaf(pj[u], x[u][1], acc[1]);
                acc[2] = fmaf(pj[u], x[u][2], acc[2]);
                acc[3] = fmaf(pj[u], x[u][3], acc[3]);
            }
        }
        for (; jj < cnt; jj += 4) {
            int eidx = jj + qw;
            int ec = (eidx < cnt) ? eidx : (cnt - 1);
            float pj = __shfl(p, ec);
            int sj = __shfl(s, ec);
            if (eidx < cnt) {
                f32x4 x = *(const f32x4*)&nfeat[(size_t)sj * DIM + ql * 4];
                acc[0] = fmaf(pj, x[0], acc[0]);
                acc[1] = fmaf(pj, x[1], acc[1]);
                acc[2] = fmaf(pj, x[2], acc[2]);
                acc[3] = fmaf(pj, x[3], acc[3]);
            }
        }
    }
#pragma unroll
    for (int ms = 32; ms; ms >>= 1) pl += __shfl_xor(pl, ms);

#pragma unroll
    for (int c = 0; c < 4; ++c) {
        acc[c] += __shfl_xor(acc[c], 16);
        acc[c] += __shfl_xor(acc[c], 32);
    }

    const float inv = (je > jb) ? 1.0f / pl : 0.f;
    if (qw == 0) {
        f32x4 hv = {acc[0] * inv, acc[1] * inv, acc[2] * inv, acc[3] * inv};
        *(f32x4*)&hn[(size_t)node * DIM + ql * 4] = hv;
    }
}

// ---------------------------------------------------------------------------
// Bi-interaction: out = lrelu((nf+hn)@W1) + lrelu((nf*hn)@W2), MFMA f16.
// ---------------------------------------------------------------------------
__global__ __launch_bounds__(256) void k_bi(const float* __restrict__ nfeat,
                                            const float* __restrict__ hn,
                                            const float* __restrict__ W1,
                                            const float* __restrict__ W2,
                                            float* __restrict__ out, int N) {
    __shared__ _Float16 shMem[4 * 64 * PA];
    _Float16* shA1 = shMem;
    _Float16* shA2 = shMem + 64 * PA;
    _Float16* shB1 = shMem + 2 * 64 * PA;
    _Float16* shB2 = shMem + 3 * 64 * PA;

    const int tx = threadIdx.x;
    const int n0 = blockIdx.x * 64;

    const float4* nf4 = (const float4*)(nfeat + (size_t)n0 * DIM);
    const float4* hn4 = (const float4*)(hn + (size_t)n0 * DIM);
#pragma unroll
    for (int i = 0; i < 4; ++i) {
        int idx = tx + 256 * i;
        int row = idx >> 4, c = idx & 15;
        bool ok = (n0 + row < N);
        float4 a = ok ? nf4[idx] : f4zero();
        float4 b = ok ? hn4[idx] : f4zero();
        _Float16* p1 = &shA1[row * PA + c * 4];
        _Float16* p2 = &shA2[row * PA + c * 4];
        p1[0] = (_Float16)(a.x + b.x); p2[0] = (_Float16)(a.x * b.x);
        p1[1] = (_Float16)(a.y + b.y); p2[1] = (_Float16)(a.y * b.y);
        p1[2] = (_Float16)(a.z + b.z); p2[2] = (_Float16)(a.z * b.z);
        p1[3] = (_Float16)(a.w + b.w); p2[3] = (_Float16)(a.w * b.w);
    }
    const float4* w14 = (const float4*)W1;
    const float4* w24 = (const float4*)W2;
#pragma unroll
    for (int i = 0; i < 4; ++i) {
        int idx = tx + 256 * i;
        int k = idx >> 4, c = (idx & 15) * 4;
        float4 v = w14[idx];
        shB1[(c + 0) * PA + k] = (_Float16)v.x;
        shB1[(c + 1) * PA + k] = (_Float16)v.y;
        shB1[(c + 2) * PA + k] = (_Float16)v.z;
        shB1[(c + 3) * PA + k] = (_Float16)v.w;
        float4 u = w24[idx];
        shB2[(c + 0) * PA + k] = (_Float16)u.x;
        shB2[(c + 1) * PA + k] = (_Float16)u.y;
        shB2[(c + 2) * PA + k] = (_Float16)u.z;
        shB2[(c + 3) * PA + k] = (_Float16)u.w;
    }
    __syncthreads();

    const int w = tx >> 6;
    const int lane = tx & 63;
    const int lm = lane & 15;
    const int lq = lane >> 4;
    const int m0 = w * 16;

    half8 a10 = *(const half8*)&shA1[(m0 + lm) * PA + 0 * 32 + lq * 8];
    half8 a11 = *(const half8*)&shA1[(m0 + lm) * PA + 1 * 32 + lq * 8];
    half8 a20 = *(const half8*)&shA2[(m0 + lm) * PA + 0 * 32 + lq * 8];
    half8 a21 = *(const half8*)&shA2[(m0 + lm) * PA + 1 * 32 + lq * 8];

    f32x4 res[4];
#pragma unroll
    for (int ct = 0; ct < 4; ++ct) {
        half8 b10 = *(const half8*)&shB1[(ct * 16 + lm) * PA + 0 * 32 + lq * 8];
        half8 b11 = *(const half8*)&shB1[(ct * 16 + lm) * PA + 1 * 32 + lq * 8];
        half8 b20 = *(const half8*)&shB2[(ct * 16 + lm) * PA + 0 * 32 + lq * 8];
        half8 b21 = *(const half8*)&shB2[(ct * 16 + lm) * PA + 1 * 32 + lq * 8];
        f32x4 c1 = {0.f, 0.f, 0.f, 0.f};
        f32x4 c2 = {0.f, 0.f, 0.f, 0.f};
        c1 = __builtin_amdgcn_mfma_f32_16x16x32_f16(a10, b10, c1, 0, 0, 0);
        c1 = __builtin_amdgcn_mfma_f32_16x16x32_f16(a11, b11, c1, 0, 0, 0);
        c2 = __builtin_amdgcn_mfma_f32_16x16x32_f16(a20, b20, c2, 0, 0, 0);
        c2 = __builtin_amdgcn_mfma_f32_16x16x32_f16(a21, b21, c2, 0, 0, 0);
#pragma unroll
        for (int i = 0; i < 4; ++i) {
            float o1 = c1[i], o2 = c2[i];
            res[ct][i] = (o1 >= 0.f ? o1 : 0.01f * o1) + (o2 >= 0.f ? o2 : 0.01f * o2);
        }
    }

    __syncthreads();
    float* shSt = (float*)shMem;   // 64*68*4 = 17408B <= 36864B
#pragma unroll
    for (int ct = 0; ct < 4; ++ct)
#pragma unroll
        for (int i = 0; i < 4; ++i)
            shSt[(m0 + lq * 4 + i) * 68 + ct * 16 + lm] = res[ct][i];
    __syncthreads();

    float* outp = out + (size_t)n0 * DIM;
#pragma unroll
    for (int k = 0; k < 4; ++k) {
        int idx = tx + 256 * k;
        int row = idx >> 4, cc = idx & 15;
        if (n0 + row < N) {
            float4 v = *(const float4*)&shSt[row * 68 + cc * 4];
            *(float4*)&outp[(size_t)row * DIM + cc * 4] = v;
        }
    }
}

extern "C" void kernel_launch(void* const* d_in, const int* in_sizes, int n_in,
                              void* d_out, int out_size, void* d_ws, size_t ws_size,
                              hipStream_t stream) {
    const float* nfeat = (const float*)d_in[0];
    const float* efeat = (const float*)d_in[1];
    const float* relW  = (const float*)d_in[2];
    const float* W1    = (const float*)d_in[3];
    const float* W2    = (const float*)d_in[4];
    const int* src   = (const int*)d_in[5];
    const int* dst   = (const int*)d_in[6];
    const int* etype = (const int*)d_in[7];

    const int N = in_sizes[0] / DIM;
    const int E = in_sizes[5];
    const int NB = (N + 255) / 256;    // dst-scan blocks (<=256)
    const int NBE = (E + 255) / 256;   // edge blocks (type hist)

    float* out = (float*)d_out;
    float* hn  = out;
    float* bi  = out + (size_t)N * DIM;

    // ws: deg[N] | off[N+1] | epart[N] | bsum[256] | rank[E] | src_s[E] |
    //     att_s[E] | bh[16*NBE] | hdr[64] | sS[E] | dS[E] | pS[E] | eS[E]
    int* deg    = (int*)d_ws;
    int* off    = deg + N;
    int* epart  = off + (N + 1);
    int* bsum   = epart + N;
    int* rank   = bsum + 256;
    int* src_s  = rank + E;
    float* att_s = (float*)(src_s + E);
    int* bh     = (int*)(att_s + E);
    int* hdr    = bh + (size_t)16 * NBE;
    int* sS     = hdr + 64;
    int* dS     = sS + E;
    int* pS     = dS + E;
    int* eS     = pS + E;

    (void)hipMemsetAsync(deg, 0, (size_t)N * sizeof(int), stream);

    k_hist<<<NBE, 256, 0, stream>>>(dst, deg, rank, E);
    k_scan1<<<NB, 256, 0, stream>>>(deg, epart, bsum, N);
    k_scan2<<<1, 1024, 0, stream>>>(epart, bsum, NB, off, N, E);

    k_thist<<<NBE, 256, 0, stream>>>(etype, bh, NBE, E);
    k_tscan<<<1, 1024, 0, stream>>>(bh, NBE, hdr);
    k_tfill<<<NBE, 256, 0, stream>>>(src, dst, etype, rank, off, bh, NBE,
                                     sS, dS, pS, eS, E);

    const int nTiles = (E + 63) / 64 + 16;   // >= actual tile count
    k_attE<<<nTiles, 256, 0, stream>>>(nfeat, efeat, relW, hdr,
                                       sS, dS, pS, eS, att_s, src_s);

    k_agg<<<(N + 3) / 4, 256, 0, stream>>>(att_s, src_s, nfeat, off, hn, N);

    k_bi<<<(N + 63) / 64, 256, 0, stream>>>(nfeat, hn, W1, W2, bi, N);
}